// Round 1
// baseline (1435.645 us; speedup 1.0000x reference)
//
#include <hip/hip_runtime.h>
#include <hip/hip_bf16.h>
#include <math.h>

// ---------------- constants ----------------
#define SEQ   4096
#define BATCH 2
#define DM    768
#define DI    1152
#define NHEAD 12
#define DH    64
#define NTOK  (BATCH * SEQ)   // 8192
#define HALFW 64              // WINDOW//2

// ---------------- RMSNorm ----------------
// one block (256 threads) per row of 768
__global__ __launch_bounds__(256)
void rmsnorm_kernel(const float* __restrict__ x, const float* __restrict__ g,
                    float* __restrict__ out) {
    const int row = blockIdx.x;
    const int t = threadIdx.x;
    const float* xr = x + (size_t)row * DM;
    float a = xr[t], b = xr[t + 256], c = xr[t + 512];
    float ss = a * a + b * b + c * c;
    #pragma unroll
    for (int o = 32; o > 0; o >>= 1) ss += __shfl_xor(ss, o);
    __shared__ float red[4];
    if ((t & 63) == 0) red[t >> 6] = ss;
    __syncthreads();
    float tot = red[0] + red[1] + red[2] + red[3];
    float inv = 1.0f / sqrtf(tot * (1.0f / DM) + 1e-5f);
    float* orow = out + (size_t)row * DM;
    orow[t]       = a * inv * g[t];
    orow[t + 256] = b * inv * g[t + 256];
    orow[t + 512] = c * inv * g[t + 512];
}

// ---------------- SGEMM (fp32, 128x128x16, 8x8 microtile split 2x2 of 4x4) ----
// EPI: 0 none, 1 gelu(tanh), 2 multiply-by-AUX.  RES: add residual R.
__device__ __forceinline__ float gelu_tanh(float v) {
    return 0.5f * v * (1.0f + tanhf(0.7978845608028654f * (v + 0.044715f * v * v * v)));
}

template<int EPI, bool RES>
__global__ __launch_bounds__(256)
void sgemm_kernel(const float* __restrict__ A, const float* __restrict__ Bm,
                  float* __restrict__ C, const float* __restrict__ R,
                  const float* __restrict__ AUX, int M, int N, int K) {
    __shared__ float As[16][132];   // [k][m], transposed A tile
    __shared__ float Bs[16][132];   // [k][n]
    const int t  = threadIdx.x;
    const int tx = t & 15, ty = t >> 4;
    const int bm = blockIdx.y, bn = blockIdx.x;

    // global-load assignments
    const int ar = t >> 2;          // 0..63   (rows ar and ar+64)
    const int ac = (t & 3) << 2;    // 0,4,8,12
    const int br = t >> 5;          // 0..7    (rows br and br+8)
    const int bc = (t & 31) << 2;   // 0..124

    const float* Ap = A + (size_t)(bm * 128 + ar) * K + ac;
    const float* Bp = Bm + (size_t)br * N + (size_t)bn * 128 + bc;

    float4 apre0 = *(const float4*)Ap;
    float4 apre1 = *(const float4*)(Ap + (size_t)64 * K);
    float4 bpre0 = *(const float4*)Bp;
    float4 bpre1 = *(const float4*)(Bp + (size_t)8 * N);

    float acc[2][2][4][4] = {};

    for (int k0 = 0; k0 < K; k0 += 16) {
        __syncthreads();
        As[ac + 0][ar] = apre0.x; As[ac + 1][ar] = apre0.y;
        As[ac + 2][ar] = apre0.z; As[ac + 3][ar] = apre0.w;
        As[ac + 0][ar + 64] = apre1.x; As[ac + 1][ar + 64] = apre1.y;
        As[ac + 2][ar + 64] = apre1.z; As[ac + 3][ar + 64] = apre1.w;
        *(float4*)&Bs[br][bc]     = bpre0;
        *(float4*)&Bs[br + 8][bc] = bpre1;
        __syncthreads();

        if (k0 + 16 < K) {
            Ap += 16; Bp += (size_t)16 * N;
            apre0 = *(const float4*)Ap;
            apre1 = *(const float4*)(Ap + (size_t)64 * K);
            bpre0 = *(const float4*)Bp;
            bpre1 = *(const float4*)(Bp + (size_t)8 * N);
        }

        #pragma unroll
        for (int k = 0; k < 16; ++k) {
            float4 a0 = *(const float4*)&As[k][ty << 2];
            float4 a1 = *(const float4*)&As[k][(ty << 2) + 64];
            float4 b0 = *(const float4*)&Bs[k][tx << 2];
            float4 b1 = *(const float4*)&Bs[k][(tx << 2) + 64];
            float av[2][4] = {{a0.x, a0.y, a0.z, a0.w}, {a1.x, a1.y, a1.z, a1.w}};
            float bv[2][4] = {{b0.x, b0.y, b0.z, b0.w}, {b1.x, b1.y, b1.z, b1.w}};
            #pragma unroll
            for (int ri = 0; ri < 2; ++ri)
                #pragma unroll
                for (int ci = 0; ci < 2; ++ci)
                    #pragma unroll
                    for (int r = 0; r < 4; ++r)
                        #pragma unroll
                        for (int c = 0; c < 4; ++c)
                            acc[ri][ci][r][c] += av[ri][r] * bv[ci][c];
        }
    }

    // epilogue
    #pragma unroll
    for (int ri = 0; ri < 2; ++ri)
        #pragma unroll
        for (int r = 0; r < 4; ++r) {
            const size_t row = (size_t)bm * 128 + ri * 64 + (ty << 2) + r;
            #pragma unroll
            for (int ci = 0; ci < 2; ++ci) {
                const size_t col = (size_t)bn * 128 + ci * 64 + (tx << 2);
                const size_t idx = row * (size_t)N + col;
                float v0 = acc[ri][ci][r][0], v1 = acc[ri][ci][r][1];
                float v2 = acc[ri][ci][r][2], v3 = acc[ri][ci][r][3];
                if (EPI == 1) {
                    v0 = gelu_tanh(v0); v1 = gelu_tanh(v1);
                    v2 = gelu_tanh(v2); v3 = gelu_tanh(v3);
                } else if (EPI == 2) {
                    float4 gv = *(const float4*)(AUX + idx);
                    v0 *= gv.x; v1 *= gv.y; v2 *= gv.z; v3 *= gv.w;
                }
                if (RES) {
                    float4 rv = *(const float4*)(R + idx);
                    v0 += rv.x; v1 += rv.y; v2 += rv.z; v3 += rv.w;
                }
                float4 o = make_float4(v0, v1, v2, v3);
                *(float4*)(C + idx) = o;
            }
        }
}

// ---------------- RoPE (in-place on qkv buffer, q and k) ----------------
__global__ __launch_bounds__(256)
void rope_kernel(float* __restrict__ qkv) {
    const int id = blockIdx.x * 256 + threadIdx.x;   // NTOK*NHEAD*32 threads
    const int j   = id & 31;
    const int hh  = (id >> 5) % NHEAD;
    const int row = id / (NHEAD * 32);
    const int s   = row & (SEQ - 1);
    float invf = (float)pow(10000.0, -(double)j / 32.0);
    float ph = (float)s * invf;
    float sn, cs;
    __sincosf(ph, &sn, &cs);   // fast path; fall back handled below
    // use accurate sincos for large-arg reduction
    sn = sinf(ph); cs = cosf(ph);
    float* base = qkv + (size_t)row * (3 * DM) + hh * DH + j;
    float q0 = base[0],   q1 = base[32];
    base[0]  = q0 * cs - q1 * sn;
    base[32] = q1 * cs + q0 * sn;
    float k0 = base[768], k1 = base[800];
    base[768] = k0 * cs - k1 * sn;
    base[800] = k1 * cs + k0 * sn;
}

// ---------------- Sliding-window attention (flash-style, fp32) ----------------
// grid: (64 q-tiles, 12 heads, 2 batch), 256 threads
__global__ __launch_bounds__(256)
void attn_kernel(const float* __restrict__ qkv, const int* __restrict__ pmask,
                 float* __restrict__ out) {
    const int qt = blockIdx.x, h = blockIdx.y, b = blockIdx.z;
    const int q0 = qt * 64;
    const int t  = threadIdx.x;
    const int tx = t & 15, ty = t >> 4;

    __shared__ float Qs[64][65];
    __shared__ float Ks[64][65];
    __shared__ float Vs[64][68];
    __shared__ float Ps[64][68];

    // ---- load Q tile (scaled by 1/8, exact pow2) ----
    {
        const int r = t >> 2;
        #pragma unroll
        for (int i = 0; i < 4; ++i) {
            const int cf = ((t & 3) + 4 * i) * 4;
            float4 v = *(const float4*)(qkv + ((size_t)(b * SEQ + q0 + r)) * (3 * DM) + h * DH + cf);
            Qs[r][cf + 0] = v.x * 0.125f; Qs[r][cf + 1] = v.y * 0.125f;
            Qs[r][cf + 2] = v.z * 0.125f; Qs[r][cf + 3] = v.w * 0.125f;
        }
    }

    float oacc[4][4] = {};
    float Mrun[4] = {-3.0e38f, -3.0e38f, -3.0e38f, -3.0e38f};
    float Lrun[4] = {};

    for (int kb = 0; kb < 3; ++kb) {
        const int kstart = q0 - 64 + kb * 64;
        __syncthreads();   // protect Ks/Vs/Ps from previous iter readers
        // ---- stage K,V tiles ----
        {
            const int r = t >> 2;
            const int kg = kstart + r;
            const bool ok = (kg >= 0 && kg < SEQ);
            const float* Krow = qkv + ((size_t)(b * SEQ + (ok ? kg : 0))) * (3 * DM) + DM + h * DH;
            #pragma unroll
            for (int i = 0; i < 4; ++i) {
                const int cf = ((t & 3) + 4 * i) * 4;
                float4 kv = ok ? *(const float4*)(Krow + cf) : make_float4(0.f, 0.f, 0.f, 0.f);
                float4 vv = ok ? *(const float4*)(Krow + DM + cf) : make_float4(0.f, 0.f, 0.f, 0.f);
                Ks[r][cf + 0] = kv.x; Ks[r][cf + 1] = kv.y;
                Ks[r][cf + 2] = kv.z; Ks[r][cf + 3] = kv.w;
                *(float4*)&Vs[r][cf] = vv;
            }
        }
        __syncthreads();

        // ---- scores: 4q x 4k microtile ----
        float sacc[4][4] = {};
        #pragma unroll 8
        for (int d = 0; d < DH; ++d) {
            float qreg[4], kreg[4];
            #pragma unroll
            for (int r = 0; r < 4; ++r) qreg[r] = Qs[4 * ty + r][d];
            #pragma unroll
            for (int c = 0; c < 4; ++c) kreg[c] = Ks[4 * tx + c][d];
            #pragma unroll
            for (int r = 0; r < 4; ++r)
                #pragma unroll
                for (int c = 0; c < 4; ++c)
                    sacc[r][c] += qreg[r] * kreg[c];
        }

        // ---- mask ----
        const int kbase = kstart + 4 * tx;
        int pm[4];
        #pragma unroll
        for (int c = 0; c < 4; ++c) {
            const int kg = kbase + c;
            pm[c] = (kg >= 0 && kg < SEQ) ? pmask[b * SEQ + kg] : 0;
        }
        #pragma unroll
        for (int r = 0; r < 4; ++r) {
            const int qg = q0 + 4 * ty + r;
            #pragma unroll
            for (int c = 0; c < 4; ++c) {
                const int kg = kbase + c;
                const int diff = qg - kg;
                const bool valid = (kg >= 0) && (kg < SEQ) &&
                                   (diff <= HALFW) && (diff >= -HALFW) && (pm[c] != 0);
                if (!valid) sacc[r][c] = -3.0e38f;
            }
        }

        // ---- online softmax update (rows shared across tx group of 16 lanes) ----
        #pragma unroll
        for (int r = 0; r < 4; ++r) {
            float m = fmaxf(fmaxf(sacc[r][0], sacc[r][1]), fmaxf(sacc[r][2], sacc[r][3]));
            #pragma unroll
            for (int o = 8; o > 0; o >>= 1) m = fmaxf(m, __shfl_xor(m, o));
            const float Mnew = fmaxf(Mrun[r], m);
            float p[4], psum = 0.f;
            #pragma unroll
            for (int c = 0; c < 4; ++c) {
                p[c] = (sacc[r][c] > -1.0e37f) ? expf(sacc[r][c] - Mnew) : 0.0f;
                psum += p[c];
            }
            #pragma unroll
            for (int o = 8; o > 0; o >>= 1) psum += __shfl_xor(psum, o);
            const float scale = expf(Mrun[r] - Mnew);
            Lrun[r] = Lrun[r] * scale + psum;
            Mrun[r] = Mnew;
            #pragma unroll
            for (int c = 0; c < 4; ++c) oacc[r][c] *= scale;
            *(float4*)&Ps[4 * ty + r][4 * tx] = make_float4(p[0], p[1], p[2], p[3]);
        }
        __syncthreads();

        // ---- PV: out += P(64x64) @ V(64x64) ----
        #pragma unroll 4
        for (int k = 0; k < 64; ++k) {
            float4 v = *(const float4*)&Vs[k][4 * tx];
            float pr[4];
            #pragma unroll
            for (int r = 0; r < 4; ++r) pr[r] = Ps[4 * ty + r][k];
            #pragma unroll
            for (int r = 0; r < 4; ++r) {
                oacc[r][0] += pr[r] * v.x;
                oacc[r][1] += pr[r] * v.y;
                oacc[r][2] += pr[r] * v.z;
                oacc[r][3] += pr[r] * v.w;
            }
        }
    }

    // ---- normalize + store ----
    #pragma unroll
    for (int r = 0; r < 4; ++r) {
        const float inv = (Lrun[r] > 0.f) ? 1.0f / Lrun[r] : 0.0f;
        float4 o = make_float4(oacc[r][0] * inv, oacc[r][1] * inv,
                               oacc[r][2] * inv, oacc[r][3] * inv);
        *(float4*)(out + ((size_t)(b * SEQ + q0 + 4 * ty + r)) * DM + h * DH + 4 * tx) = o;
    }
}

// ---------------- driver ----------------
extern "C" void kernel_launch(void* const* d_in, const int* in_sizes, int n_in,
                              void* d_out, int out_size, void* d_ws, size_t ws_size,
                              hipStream_t stream) {
    const float* x      = (const float*)d_in[0];
    const int*   pmask  = (const int*)  d_in[1];
    const float* w_qkv  = (const float*)d_in[2];
    const float* w_o    = (const float*)d_in[3];
    const float* g_attn = (const float*)d_in[4];
    const float* g_mlp  = (const float*)d_in[5];
    const float* w_i0   = (const float*)d_in[6];
    const float* w_i1   = (const float*)d_in[7];
    const float* w_mo   = (const float*)d_in[8];
    float* out = (float*)d_out;

    float* bufA = (float*)d_ws;                        // NTOK*768  (h / attn_out / h2)
    float* bufB = bufA + (size_t)NTOK * DM;            // NTOK*2304 (qkv, later gate+prod)
    float* gate = bufB;                                // NTOK*1152
    float* prod = bufB + (size_t)NTOK * DI;            // NTOK*1152

    // 1. h = rmsnorm(x, gamma_attn)
    rmsnorm_kernel<<<NTOK, 256, 0, stream>>>(x, g_attn, bufA);
    // 2. qkv = h @ w_qkv   (8192 x 2304 x 768)
    sgemm_kernel<0, false><<<dim3(3 * DM / 128, NTOK / 128), 256, 0, stream>>>(
        bufA, w_qkv, bufB, nullptr, nullptr, NTOK, 3 * DM, DM);
    // 3. rope(q, k) in-place
    rope_kernel<<<(NTOK * NHEAD * 32) / 256, 256, 0, stream>>>(bufB);
    // 4. attn_out = SWA(q,k,v)  -> bufA
    attn_kernel<<<dim3(SEQ / 64, NHEAD, BATCH), 256, 0, stream>>>(bufB, pmask, bufA);
    // 5. x1 = x + attn_out @ w_o  -> d_out
    sgemm_kernel<0, true><<<dim3(DM / 128, NTOK / 128), 256, 0, stream>>>(
        bufA, w_o, out, x, nullptr, NTOK, DM, DM);
    // 6. h2 = rmsnorm(x1, gamma_mlp) -> bufA
    rmsnorm_kernel<<<NTOK, 256, 0, stream>>>(out, g_mlp, bufA);
    // 7. gate = gelu(h2 @ w_i0)
    sgemm_kernel<1, false><<<dim3(DI / 128, NTOK / 128), 256, 0, stream>>>(
        bufA, w_i0, gate, nullptr, nullptr, NTOK, DI, DM);
    // 8. prod = (h2 @ w_i1) * gate
    sgemm_kernel<2, false><<<dim3(DI / 128, NTOK / 128), 256, 0, stream>>>(
        bufA, w_i1, prod, nullptr, gate, NTOK, DI, DM);
    // 9. out = x1 + prod @ w_mo   (in-place residual on d_out)
    sgemm_kernel<0, true><<<dim3(DM / 128, NTOK / 128), 256, 0, stream>>>(
        prod, w_mo, out, out, nullptr, NTOK, DM, DI);
}

// Round 2
// 433.723 us; speedup vs baseline: 3.3100x; 3.3100x over previous
//
#include <hip/hip_runtime.h>
#include <hip/hip_bf16.h>
#include <math.h>

// ---------------- constants ----------------
#define SEQ   4096
#define BATCH 2
#define DM    768
#define DI    1152
#define NHEAD 12
#define DH    64
#define NTOK  (BATCH * SEQ)   // 8192
#define HALFW 64              // WINDOW//2

typedef unsigned short u16;
typedef __attribute__((ext_vector_type(8))) short   short8;   // 8 bf16 = MFMA A/B frag
typedef __attribute__((ext_vector_type(4))) float   f32x4;    // MFMA C/D frag
typedef __attribute__((ext_vector_type(8))) unsigned short ushort8;
typedef __attribute__((ext_vector_type(4))) unsigned short ushort4v;

__device__ __forceinline__ u16 f2bf(float f) {
    unsigned int u = __float_as_uint(f);
    u += 0x7fffu + ((u >> 16) & 1u);   // RNE
    return (u16)(u >> 16);
}
__device__ __forceinline__ float bf2f(u16 b) {
    return __uint_as_float(((unsigned int)b) << 16);
}

__device__ __forceinline__ void gload16(const void* g, void* l) {
    __builtin_amdgcn_global_load_lds(
        (const __attribute__((address_space(1))) void*)g,
        (__attribute__((address_space(3))) void*)l, 16, 0, 0);
}

__device__ __forceinline__ float gelu_tanh(float v) {
    return 0.5f * v * (1.0f + tanhf(0.7978845608028654f * (v + 0.044715f * v * v * v)));
}

// ---------------- weight transpose + bf16 convert ----------------
// W: fp32 [K][N] row-major  ->  WT: bf16 [N][K] row-major
__global__ __launch_bounds__(256)
void wtrans_kernel(const float* __restrict__ W, u16* __restrict__ WT, int K, int N) {
    __shared__ float S[32][33];
    const int tn = blockIdx.x, tk = blockIdx.y;
    const int tx = threadIdx.x & 31, ty = threadIdx.x >> 5;   // ty: 0..7
    #pragma unroll
    for (int i = 0; i < 4; ++i) {
        const int r = ty + i * 8;
        S[r][tx] = W[(size_t)(tk * 32 + r) * N + tn * 32 + tx];
    }
    __syncthreads();
    #pragma unroll
    for (int i = 0; i < 4; ++i) {
        const int r = ty + i * 8;   // n within tile
        WT[(size_t)(tn * 32 + r) * K + tk * 32 + tx] = f2bf(S[tx][r]);
    }
}

// ---------------- RMSNorm (fp32 in -> bf16 out) ----------------
__global__ __launch_bounds__(256)
void rmsnorm_kernel(const float* __restrict__ x, const float* __restrict__ g,
                    u16* __restrict__ out) {
    const int row = blockIdx.x;
    const int t = threadIdx.x;
    const float* xr = x + (size_t)row * DM;
    float a = xr[t], b = xr[t + 256], c = xr[t + 512];
    float ss = a * a + b * b + c * c;
    #pragma unroll
    for (int o = 32; o > 0; o >>= 1) ss += __shfl_xor(ss, o);
    __shared__ float red[4];
    if ((t & 63) == 0) red[t >> 6] = ss;
    __syncthreads();
    float tot = red[0] + red[1] + red[2] + red[3];
    float inv = 1.0f / sqrtf(tot * (1.0f / DM) + 1e-5f);
    u16* orow = out + (size_t)row * DM;
    orow[t]       = f2bf(a * inv * g[t]);
    orow[t + 256] = f2bf(b * inv * g[t + 256]);
    orow[t + 512] = f2bf(c * inv * g[t + 512]);
}

// ---------------- bf16 MFMA GEMM: C[M][N] = A[M][K] @ B'[N][K]^T ----------------
// A bf16 row-major [M][K]; B bf16 row-major [N][K] (pre-transposed weight).
// EPI: 0 none, 1 gelu, 2 *AUX(fp32).  RES: += R(fp32).  OBF: bf16 out else fp32.
// 128x128 tile, BK=32, 4 waves (2x2 of 64x64), 16x16x32 MFMA.
template<int EPI, bool RES, bool OBF>
__global__ __launch_bounds__(256)
void bgemm_kernel(const u16* __restrict__ A, const u16* __restrict__ B,
                  void* __restrict__ Cv, const float* __restrict__ R,
                  const float* __restrict__ AUX, int M, int N, int K) {
    __shared__ u16 As[4096];   // 128 rows x 32 k, XOR-swizzled 16B slots
    __shared__ u16 Bs[4096];
    const int t = threadIdx.x;
    const int w = t >> 6, l = t & 63;
    const int wm = w >> 1, wn = w & 1;
    const int bm = blockIdx.y, bn = blockIdx.x;

    // staging: slot s holds row m=s>>2, k-chunk ksrc=( (s&3) ^ ((s>>3)&3) )
    const int s0 = (w * 2 + 0) * 64 + l;
    const int s1 = (w * 2 + 1) * 64 + l;
    const int am0 = s0 >> 2, ak0 = ((s0 & 3) ^ ((s0 >> 3) & 3)) * 8;
    const int am1 = s1 >> 2, ak1 = ((s1 & 3) ^ ((s1 >> 3) & 3)) * 8;
    const u16* aSrc0 = A + (size_t)(bm * 128 + am0) * K + ak0;
    const u16* aSrc1 = A + (size_t)(bm * 128 + am1) * K + ak1;
    const u16* bSrc0 = B + (size_t)(bn * 128 + am0) * K + ak0;
    const u16* bSrc1 = B + (size_t)(bn * 128 + am1) * K + ak1;
    u16* aDst0 = As + (size_t)(w * 2 + 0) * 512;
    u16* aDst1 = As + (size_t)(w * 2 + 1) * 512;
    u16* bDst0 = Bs + (size_t)(w * 2 + 0) * 512;
    u16* bDst1 = Bs + (size_t)(w * 2 + 1) * 512;

    const int lm = l & 15, lk = l >> 4;
    const int xoff = ((lk ^ ((lm >> 1) & 3)) * 16);   // byte offset within 64B row
    const char* Abase = (const char*)As;
    const char* Bbase = (const char*)Bs;

    f32x4 acc[4][4] = {};

    const int nk = K >> 5;
    for (int kt = 0; kt < nk; ++kt) {
        gload16(aSrc0, aDst0);
        gload16(aSrc1, aDst1);
        gload16(bSrc0, bDst0);
        gload16(bSrc1, bDst1);
        aSrc0 += 32; aSrc1 += 32; bSrc0 += 32; bSrc1 += 32;
        __syncthreads();   // drains vmcnt: tile ready

        short8 af[4], bfr[4];
        #pragma unroll
        for (int i = 0; i < 4; ++i) {
            af[i]  = *(const short8*)(Abase + (wm * 64 + i * 16 + lm) * 64 + xoff);
            bfr[i] = *(const short8*)(Bbase + (wn * 64 + i * 16 + lm) * 64 + xoff);
        }
        #pragma unroll
        for (int i = 0; i < 4; ++i)
            #pragma unroll
            for (int j = 0; j < 4; ++j)
                acc[i][j] = __builtin_amdgcn_mfma_f32_16x16x32_bf16(af[i], bfr[j], acc[i][j], 0, 0, 0);
        __syncthreads();   // all reads done before next tile overwrites
    }

    // epilogue: D[row=(l>>4)*4+r][col=l&15]
    const int lg = l >> 4;
    float* Cf = (float*)Cv;
    u16*   Cb = (u16*)Cv;
    #pragma unroll
    for (int i = 0; i < 4; ++i) {
        const size_t row0 = (size_t)bm * 128 + wm * 64 + i * 16 + lg * 4;
        #pragma unroll
        for (int j = 0; j < 4; ++j) {
            const size_t col = (size_t)bn * 128 + wn * 64 + j * 16 + lm;
            #pragma unroll
            for (int r = 0; r < 4; ++r) {
                const size_t idx = (row0 + r) * (size_t)N + col;
                float v = acc[i][j][r];
                if (EPI == 1)      v = gelu_tanh(v);
                else if (EPI == 2) v *= AUX[idx];
                if (RES)           v += R[idx];
                if (OBF) Cb[idx] = f2bf(v);
                else     Cf[idx] = v;
            }
        }
    }
}

// ---------------- RoPE (in-place on bf16 qkv, q and k) ----------------
__global__ __launch_bounds__(256)
void rope_kernel(u16* __restrict__ qkv) {
    const int id = blockIdx.x * 256 + threadIdx.x;   // NTOK*NHEAD*32 threads
    const int j   = id & 31;
    const int hh  = (id >> 5) % NHEAD;
    const int row = id / (NHEAD * 32);
    const int s   = row & (SEQ - 1);
    const float invf = powf(10000.0f, -(float)j * (1.0f / 32.0f));
    const float ph = (float)s * invf;
    const float sn = sinf(ph), cs = cosf(ph);
    u16* base = qkv + (size_t)row * (3 * DM) + hh * DH + j;
    float q0 = bf2f(base[0]), q1 = bf2f(base[32]);
    base[0]  = f2bf(q0 * cs - q1 * sn);
    base[32] = f2bf(q1 * cs + q0 * sn);
    float k0 = bf2f(base[DM]), k1 = bf2f(base[DM + 32]);
    base[DM]      = f2bf(k0 * cs - k1 * sn);
    base[DM + 32] = f2bf(k1 * cs + k0 * sn);
}

// ---------------- Sliding-window attention (bf16 io, fp32 math) ----------------
__global__ __launch_bounds__(256)
void attn_kernel(const u16* __restrict__ qkv, const int* __restrict__ pmask,
                 u16* __restrict__ out) {
    const int qt = blockIdx.x, h = blockIdx.y, b = blockIdx.z;
    const int q0 = qt * 64;
    const int t  = threadIdx.x;
    const int tx = t & 15, ty = t >> 4;

    __shared__ float Qs[64][65];
    __shared__ float Ks[64][65];
    __shared__ float Vs[64][68];
    __shared__ float Ps[64][68];

    // ---- load Q tile (scaled by 1/8) ----
    {
        const int r = t >> 2;
        const u16* Qrow = qkv + (size_t)(b * SEQ + q0 + r) * (3 * DM) + h * DH;
        #pragma unroll
        for (int i = 0; i < 2; ++i) {
            const int c0 = (t & 3) * 16 + i * 8;
            ushort8 v = *(const ushort8*)(Qrow + c0);
            #pragma unroll
            for (int e = 0; e < 8; ++e) Qs[r][c0 + e] = bf2f(v[e]) * 0.125f;
        }
    }

    float oacc[4][4] = {};
    float Mrun[4] = {-3.0e38f, -3.0e38f, -3.0e38f, -3.0e38f};
    float Lrun[4] = {};

    for (int kb = 0; kb < 3; ++kb) {
        const int kstart = q0 - 64 + kb * 64;
        __syncthreads();
        // ---- stage K,V tiles ----
        {
            const int r = t >> 2;
            const int kg = kstart + r;
            const bool ok = (kg >= 0 && kg < SEQ);
            const u16* Krow = qkv + (size_t)(b * SEQ + (ok ? kg : 0)) * (3 * DM) + DM + h * DH;
            #pragma unroll
            for (int i = 0; i < 2; ++i) {
                const int c0 = (t & 3) * 16 + i * 8;
                ushort8 kv = *(const ushort8*)(Krow + c0);
                ushort8 vv = *(const ushort8*)(Krow + DM + c0);
                #pragma unroll
                for (int e = 0; e < 8; ++e) {
                    Ks[r][c0 + e] = ok ? bf2f(kv[e]) : 0.0f;
                    Vs[r][c0 + e] = ok ? bf2f(vv[e]) : 0.0f;
                }
            }
        }
        __syncthreads();

        // ---- scores: 4q x 4k microtile ----
        float sacc[4][4] = {};
        #pragma unroll 8
        for (int d = 0; d < DH; ++d) {
            float qreg[4], kreg[4];
            #pragma unroll
            for (int r = 0; r < 4; ++r) qreg[r] = Qs[4 * ty + r][d];
            #pragma unroll
            for (int c = 0; c < 4; ++c) kreg[c] = Ks[4 * tx + c][d];
            #pragma unroll
            for (int r = 0; r < 4; ++r)
                #pragma unroll
                for (int c = 0; c < 4; ++c)
                    sacc[r][c] += qreg[r] * kreg[c];
        }

        // ---- mask ----
        const int kbase = kstart + 4 * tx;
        int pm[4];
        #pragma unroll
        for (int c = 0; c < 4; ++c) {
            const int kg = kbase + c;
            pm[c] = (kg >= 0 && kg < SEQ) ? pmask[b * SEQ + kg] : 0;
        }
        #pragma unroll
        for (int r = 0; r < 4; ++r) {
            const int qg = q0 + 4 * ty + r;
            #pragma unroll
            for (int c = 0; c < 4; ++c) {
                const int kg = kbase + c;
                const int diff = qg - kg;
                const bool valid = (kg >= 0) && (kg < SEQ) &&
                                   (diff <= HALFW) && (diff >= -HALFW) && (pm[c] != 0);
                if (!valid) sacc[r][c] = -3.0e38f;
            }
        }

        // ---- online softmax ----
        #pragma unroll
        for (int r = 0; r < 4; ++r) {
            float m = fmaxf(fmaxf(sacc[r][0], sacc[r][1]), fmaxf(sacc[r][2], sacc[r][3]));
            #pragma unroll
            for (int o = 8; o > 0; o >>= 1) m = fmaxf(m, __shfl_xor(m, o));
            const float Mnew = fmaxf(Mrun[r], m);
            float p[4], psum = 0.f;
            #pragma unroll
            for (int c = 0; c < 4; ++c) {
                p[c] = (sacc[r][c] > -1.0e37f) ? expf(sacc[r][c] - Mnew) : 0.0f;
                psum += p[c];
            }
            #pragma unroll
            for (int o = 8; o > 0; o >>= 1) psum += __shfl_xor(psum, o);
            const float scale = expf(Mrun[r] - Mnew);
            Lrun[r] = Lrun[r] * scale + psum;
            Mrun[r] = Mnew;
            #pragma unroll
            for (int c = 0; c < 4; ++c) oacc[r][c] *= scale;
            *(float4*)&Ps[4 * ty + r][4 * tx] = make_float4(p[0], p[1], p[2], p[3]);
        }
        __syncthreads();

        // ---- PV ----
        #pragma unroll 4
        for (int k = 0; k < 64; ++k) {
            float4 v = *(const float4*)&Vs[k][4 * tx];
            float pr[4];
            #pragma unroll
            for (int r = 0; r < 4; ++r) pr[r] = Ps[4 * ty + r][k];
            #pragma unroll
            for (int r = 0; r < 4; ++r) {
                oacc[r][0] += pr[r] * v.x;
                oacc[r][1] += pr[r] * v.y;
                oacc[r][2] += pr[r] * v.z;
                oacc[r][3] += pr[r] * v.w;
            }
        }
    }

    // ---- normalize + store bf16 ----
    #pragma unroll
    for (int r = 0; r < 4; ++r) {
        const float inv = (Lrun[r] > 0.f) ? 1.0f / Lrun[r] : 0.0f;
        ushort4v o;
        o[0] = f2bf(oacc[r][0] * inv); o[1] = f2bf(oacc[r][1] * inv);
        o[2] = f2bf(oacc[r][2] * inv); o[3] = f2bf(oacc[r][3] * inv);
        *(ushort4v*)(out + (size_t)(b * SEQ + q0 + 4 * ty + r) * DM + h * DH + 4 * tx) = o;
    }
}

// ---------------- driver ----------------
extern "C" void kernel_launch(void* const* d_in, const int* in_sizes, int n_in,
                              void* d_out, int out_size, void* d_ws, size_t ws_size,
                              hipStream_t stream) {
    const float* x      = (const float*)d_in[0];
    const int*   pmask  = (const int*)  d_in[1];
    const float* w_qkv  = (const float*)d_in[2];
    const float* w_o    = (const float*)d_in[3];
    const float* g_attn = (const float*)d_in[4];
    const float* g_mlp  = (const float*)d_in[5];
    const float* w_i0   = (const float*)d_in[6];
    const float* w_i1   = (const float*)d_in[7];
    const float* w_mo   = (const float*)d_in[8];
    float* out = (float*)d_out;

    char* ws = (char*)d_ws;
    u16* Wqkv = (u16*)ws;                          ws += (size_t)768 * 2304 * 2;
    u16* Wo   = (u16*)ws;                          ws += (size_t)768 * 768 * 2;
    u16* Wi0  = (u16*)ws;                          ws += (size_t)768 * 1152 * 2;
    u16* Wi1  = (u16*)ws;                          ws += (size_t)768 * 1152 * 2;
    u16* Wmo  = (u16*)ws;                          ws += (size_t)1152 * 768 * 2;
    u16* hB    = (u16*)ws;                         ws += (size_t)NTOK * DM * 2;
    u16* qkvB  = (u16*)ws;                         ws += (size_t)NTOK * 3 * DM * 2;
    u16* attnB = (u16*)ws;                         ws += (size_t)NTOK * DM * 2;
    u16* prodB = (u16*)ws;                         ws += (size_t)NTOK * DI * 2;
    float* gateF = (float*)qkvB;   // reuse: qkv dead after attention

    // 0. weight transpose+convert  W[K][N] -> bf16 [N][K]
    wtrans_kernel<<<dim3(2304 / 32, 768 / 32), 256, 0, stream>>>(w_qkv, Wqkv, 768, 2304);
    wtrans_kernel<<<dim3(768 / 32, 768 / 32),  256, 0, stream>>>(w_o,   Wo,   768, 768);
    wtrans_kernel<<<dim3(1152 / 32, 768 / 32), 256, 0, stream>>>(w_i0,  Wi0,  768, 1152);
    wtrans_kernel<<<dim3(1152 / 32, 768 / 32), 256, 0, stream>>>(w_i1,  Wi1,  768, 1152);
    wtrans_kernel<<<dim3(768 / 32, 1152 / 32), 256, 0, stream>>>(w_mo,  Wmo,  1152, 768);

    // 1. h = rmsnorm(x) -> bf16
    rmsnorm_kernel<<<NTOK, 256, 0, stream>>>(x, g_attn, hB);
    // 2. qkv = h @ w_qkv -> bf16
    bgemm_kernel<0, false, true><<<dim3(2304 / 128, NTOK / 128), 256, 0, stream>>>(
        hB, Wqkv, qkvB, nullptr, nullptr, NTOK, 2304, 768);
    // 3. rope in-place
    rope_kernel<<<(NTOK * NHEAD * 32) / 256, 256, 0, stream>>>(qkvB);
    // 4. attention -> bf16
    attn_kernel<<<dim3(SEQ / 64, NHEAD, BATCH), 256, 0, stream>>>(qkvB, pmask, attnB);
    // 5. x1 = x + attn @ w_o -> fp32 d_out
    bgemm_kernel<0, true, false><<<dim3(768 / 128, NTOK / 128), 256, 0, stream>>>(
        attnB, Wo, out, x, nullptr, NTOK, 768, 768);
    // 6. h2 = rmsnorm(x1) -> bf16
    rmsnorm_kernel<<<NTOK, 256, 0, stream>>>(out, g_mlp, hB);
    // 7. gate = gelu(h2 @ w_i0) -> fp32
    bgemm_kernel<1, false, false><<<dim3(1152 / 128, NTOK / 128), 256, 0, stream>>>(
        hB, Wi0, gateF, nullptr, nullptr, NTOK, 1152, 768);
    // 8. prod = (h2 @ w_i1) * gate -> bf16
    bgemm_kernel<2, false, true><<<dim3(1152 / 128, NTOK / 128), 256, 0, stream>>>(
        hB, Wi1, prodB, nullptr, gateF, NTOK, 1152, 768);
    // 9. out = x1 + prod @ w_mo  (in-place residual)
    bgemm_kernel<0, true, false><<<dim3(768 / 128, NTOK / 128), 256, 0, stream>>>(
        prodB, Wmo, out, out, nullptr, NTOK, 768, 1152);
}

// Round 3
// 371.960 us; speedup vs baseline: 3.8597x; 1.1660x over previous
//
#include <hip/hip_runtime.h>
#include <hip/hip_bf16.h>
#include <math.h>

// ---------------- constants ----------------
#define SEQ   4096
#define BATCH 2
#define DM    768
#define DI    1152
#define NHEAD 12
#define DH    64
#define NTOK  (BATCH * SEQ)   // 8192
#define HALFW 64              // WINDOW//2

typedef unsigned short u16;
typedef __attribute__((ext_vector_type(8))) short   short8;   // 8 bf16 = MFMA A/B frag
typedef __attribute__((ext_vector_type(4))) float   f32x4;    // MFMA C/D frag
typedef __attribute__((ext_vector_type(8))) unsigned short ushort8;

__device__ __forceinline__ u16 f2bf(float f) {
    unsigned int u = __float_as_uint(f);
    u += 0x7fffu + ((u >> 16) & 1u);   // RNE
    return (u16)(u >> 16);
}
__device__ __forceinline__ float bf2f(u16 b) {
    return __uint_as_float(((unsigned int)b) << 16);
}

__device__ __forceinline__ void gload16(const void* g, void* l) {
    __builtin_amdgcn_global_load_lds(
        (const __attribute__((address_space(1))) void*)g,
        (__attribute__((address_space(3))) void*)l, 16, 0, 0);
}

__device__ __forceinline__ float gelu_tanh(float v) {
    return 0.5f * v * (1.0f + tanhf(0.7978845608028654f * (v + 0.044715f * v * v * v)));
}

// ---------------- weight transpose + bf16 convert ----------------
__global__ __launch_bounds__(256)
void wtrans_kernel(const float* __restrict__ W, u16* __restrict__ WT, int K, int N) {
    __shared__ float S[32][33];
    const int tn = blockIdx.x, tk = blockIdx.y;
    const int tx = threadIdx.x & 31, ty = threadIdx.x >> 5;
    #pragma unroll
    for (int i = 0; i < 4; ++i) {
        const int r = ty + i * 8;
        S[r][tx] = W[(size_t)(tk * 32 + r) * N + tn * 32 + tx];
    }
    __syncthreads();
    #pragma unroll
    for (int i = 0; i < 4; ++i) {
        const int r = ty + i * 8;
        WT[(size_t)(tn * 32 + r) * K + tk * 32 + tx] = f2bf(S[tx][r]);
    }
}

// ---------------- rope cos/sin table: [s][j], j=0..31 ----------------
__global__ __launch_bounds__(256)
void rope_table_kernel(float* __restrict__ cosT, float* __restrict__ sinT) {
    const int id = blockIdx.x * 256 + threadIdx.x;   // SEQ*32
    const int j = id & 31, s = id >> 5;
    const float inv = powf(10000.0f, -(float)j * (1.0f / 32.0f));
    const float ph = (float)s * inv;
    cosT[id] = cosf(ph);
    sinT[id] = sinf(ph);
}

// ---------------- RMSNorm (fp32 in -> bf16 out) ----------------
__global__ __launch_bounds__(256)
void rmsnorm_kernel(const float* __restrict__ x, const float* __restrict__ g,
                    u16* __restrict__ out) {
    const int row = blockIdx.x;
    const int t = threadIdx.x;
    const float* xr = x + (size_t)row * DM;
    float a = xr[t], b = xr[t + 256], c = xr[t + 512];
    float ss = a * a + b * b + c * c;
    #pragma unroll
    for (int o = 32; o > 0; o >>= 1) ss += __shfl_xor(ss, o);
    __shared__ float red[4];
    if ((t & 63) == 0) red[t >> 6] = ss;
    __syncthreads();
    float tot = red[0] + red[1] + red[2] + red[3];
    float inv = 1.0f / sqrtf(tot * (1.0f / DM) + 1e-5f);
    u16* orow = out + (size_t)row * DM;
    orow[t]       = f2bf(a * inv * g[t]);
    orow[t + 256] = f2bf(b * inv * g[t + 256]);
    orow[t + 512] = f2bf(c * inv * g[t + 512]);
}

// ---------------- bf16 MFMA GEMM ----------------
// A bf16 [M][K]; B (and B2) bf16 [N][K] pre-transposed.
// EPI: 0 none, 3 swiglu (gelu(acc1)*acc2, needs DUAL).  RES: += R(fp32).
// OBF: bf16 out else fp32.
template<int EPI, bool RES, bool OBF, bool DUAL>
__global__ __launch_bounds__(256)
void bgemm_kernel(const u16* __restrict__ A, const u16* __restrict__ B,
                  const u16* __restrict__ B2, void* __restrict__ Cv,
                  const float* __restrict__ R, int M, int N, int K) {
    __shared__ u16 As[4096];
    __shared__ u16 Bs[4096];
    __shared__ u16 B2s[DUAL ? 4096 : 2];
    const int t = threadIdx.x;
    const int w = t >> 6, l = t & 63;
    const int wm = w >> 1, wn = w & 1;
    const int bm = blockIdx.y, bn = blockIdx.x;

    const int s0 = (w * 2 + 0) * 64 + l;
    const int s1 = (w * 2 + 1) * 64 + l;
    const int am0 = s0 >> 2, ak0 = ((s0 & 3) ^ ((s0 >> 3) & 3)) * 8;
    const int am1 = s1 >> 2, ak1 = ((s1 & 3) ^ ((s1 >> 3) & 3)) * 8;
    const u16* aSrc0 = A + (size_t)(bm * 128 + am0) * K + ak0;
    const u16* aSrc1 = A + (size_t)(bm * 128 + am1) * K + ak1;
    const u16* bSrc0 = B + (size_t)(bn * 128 + am0) * K + ak0;
    const u16* bSrc1 = B + (size_t)(bn * 128 + am1) * K + ak1;
    const u16* cSrc0 = DUAL ? B2 + (size_t)(bn * 128 + am0) * K + ak0 : nullptr;
    const u16* cSrc1 = DUAL ? B2 + (size_t)(bn * 128 + am1) * K + ak1 : nullptr;
    u16* aDst0 = As + (size_t)(w * 2 + 0) * 512;
    u16* aDst1 = As + (size_t)(w * 2 + 1) * 512;
    u16* bDst0 = Bs + (size_t)(w * 2 + 0) * 512;
    u16* bDst1 = Bs + (size_t)(w * 2 + 1) * 512;
    u16* cDst0 = DUAL ? B2s + (size_t)(w * 2 + 0) * 512 : nullptr;
    u16* cDst1 = DUAL ? B2s + (size_t)(w * 2 + 1) * 512 : nullptr;

    const int lm = l & 15, lk = l >> 4;
    const int xoff = ((lk ^ ((lm >> 1) & 3)) * 16);
    const char* Abase = (const char*)As;
    const char* Bbase = (const char*)Bs;
    const char* Cbase = (const char*)B2s;

    f32x4 acc[4][4] = {};
    f32x4 acc2[4][4] = {};

    const int nk = K >> 5;
    for (int kt = 0; kt < nk; ++kt) {
        gload16(aSrc0, aDst0);
        gload16(aSrc1, aDst1);
        gload16(bSrc0, bDst0);
        gload16(bSrc1, bDst1);
        if (DUAL) { gload16(cSrc0, cDst0); gload16(cSrc1, cDst1); }
        aSrc0 += 32; aSrc1 += 32; bSrc0 += 32; bSrc1 += 32;
        if (DUAL) { cSrc0 += 32; cSrc1 += 32; }
        __syncthreads();

        short8 af[4], bfr[4], cfr[4];
        #pragma unroll
        for (int i = 0; i < 4; ++i) {
            af[i]  = *(const short8*)(Abase + (wm * 64 + i * 16 + lm) * 64 + xoff);
            bfr[i] = *(const short8*)(Bbase + (wn * 64 + i * 16 + lm) * 64 + xoff);
            if (DUAL) cfr[i] = *(const short8*)(Cbase + (wn * 64 + i * 16 + lm) * 64 + xoff);
        }
        #pragma unroll
        for (int i = 0; i < 4; ++i)
            #pragma unroll
            for (int j = 0; j < 4; ++j) {
                acc[i][j] = __builtin_amdgcn_mfma_f32_16x16x32_bf16(af[i], bfr[j], acc[i][j], 0, 0, 0);
                if (DUAL)
                    acc2[i][j] = __builtin_amdgcn_mfma_f32_16x16x32_bf16(af[i], cfr[j], acc2[i][j], 0, 0, 0);
            }
        __syncthreads();
    }

    const int lg = l >> 4;
    float* Cf = (float*)Cv;
    u16*   Cb = (u16*)Cv;
    #pragma unroll
    for (int i = 0; i < 4; ++i) {
        const size_t row0 = (size_t)bm * 128 + wm * 64 + i * 16 + lg * 4;
        #pragma unroll
        for (int j = 0; j < 4; ++j) {
            const size_t col = (size_t)bn * 128 + wn * 64 + j * 16 + lm;
            #pragma unroll
            for (int r = 0; r < 4; ++r) {
                const size_t idx = (row0 + r) * (size_t)N + col;
                float v = acc[i][j][r];
                if (EPI == 3) v = gelu_tanh(v) * acc2[i][j][r];
                if (RES)      v += R[idx];
                if (OBF) Cb[idx] = f2bf(v);
                else     Cf[idx] = v;
            }
        }
    }
}

// ---------------- MFMA sliding-window attention w/ fused RoPE ----------------
// grid (SEQ/64, NHEAD, BATCH), 256 threads = 4 waves; wave w owns q rows w*16..+16.
// LDS tiles 64x64 bf16, rows = 128B, 16B-chunk XOR swizzle (chunk ^= row&7).
__device__ __forceinline__ u16* ldsAddr(u16* base, int row, int col) {
    const int ch = (col >> 3) ^ (row & 7);
    return base + row * 64 + ch * 8 + (col & 7);
}

__global__ __launch_bounds__(256)
void attn_kernel(const u16* __restrict__ qkv, const int* __restrict__ pmask,
                 const float* __restrict__ cosT, const float* __restrict__ sinT,
                 u16* __restrict__ out) {
    const int qt = blockIdx.x, h = blockIdx.y, b = blockIdx.z;
    const int q0 = qt * 64;
    const int t = threadIdx.x;
    const int w = t >> 6, l = t & 63;
    const int lm = l & 15, lg = l >> 4;

    __shared__ u16 Qs[64 * 64];
    __shared__ u16 Ks[64 * 64];
    __shared__ u16 Vt[64 * 64];   // transposed: rows = d, cols = key
    __shared__ u16 Ps[64 * 64];

    // ---- stage Q with rope (rows r=t>>2, j0=(t&3)*8) ----
    {
        const int r = t >> 2, j0 = (t & 3) * 8;
        const int s = q0 + r;
        const u16* qrow = qkv + (size_t)(b * SEQ + s) * (3 * DM) + h * DH;
        ushort8 lo = *(const ushort8*)(qrow + j0);
        ushort8 hi = *(const ushort8*)(qrow + j0 + 32);
        const float* cr = cosT + (size_t)s * 32 + j0;
        const float* sr = sinT + (size_t)s * 32 + j0;
        ushort8 olo, ohi;
        #pragma unroll
        for (int e = 0; e < 8; ++e) {
            float c = cr[e], sn = sr[e];
            float xl = bf2f(lo[e]), xh = bf2f(hi[e]);
            olo[e] = f2bf(xl * c - xh * sn);
            ohi[e] = f2bf(xh * c + xl * sn);
        }
        *(ushort8*)ldsAddr(Qs, r, j0)      = olo;
        *(ushort8*)ldsAddr(Qs, r, j0 + 32) = ohi;
    }

    f32x4 oacc[4] = {};
    float Mrun[4], Lrun[4];
    #pragma unroll
    for (int r = 0; r < 4; ++r) { Mrun[r] = -3.0e38f; Lrun[r] = 0.f; }

    for (int kb = 0; kb < 3; ++kb) {
        const int kstart = q0 - 64 + kb * 64;
        __syncthreads();   // previous tile fully consumed (also orders Q for kb=0)
        // ---- stage K with rope ----
        {
            const int r = t >> 2, j0 = (t & 3) * 8;
            const int kg = kstart + r;
            ushort8 olo = {}, ohi = {};
            if (kg >= 0 && kg < SEQ) {
                const u16* krow = qkv + (size_t)(b * SEQ + kg) * (3 * DM) + DM + h * DH;
                ushort8 lo = *(const ushort8*)(krow + j0);
                ushort8 hi = *(const ushort8*)(krow + j0 + 32);
                const float* cr = cosT + (size_t)kg * 32 + j0;
                const float* sr = sinT + (size_t)kg * 32 + j0;
                #pragma unroll
                for (int e = 0; e < 8; ++e) {
                    float c = cr[e], sn = sr[e];
                    float xl = bf2f(lo[e]), xh = bf2f(hi[e]);
                    olo[e] = f2bf(xl * c - xh * sn);
                    ohi[e] = f2bf(xh * c + xl * sn);
                }
            }
            *(ushort8*)ldsAddr(Ks, r, j0)      = olo;
            *(ushort8*)ldsAddr(Ks, r, j0 + 32) = ohi;
        }
        // ---- stage V transposed (key = l, d block = w*16..+16) ----
        {
            const int key = l;
            const int kg = kstart + key;
            const int d0 = w * 16;
            if (kg >= 0 && kg < SEQ) {
                const u16* vrow = qkv + (size_t)(b * SEQ + kg) * (3 * DM) + 2 * DM + h * DH + d0;
                ushort8 v0 = *(const ushort8*)(vrow);
                ushort8 v1 = *(const ushort8*)(vrow + 8);
                #pragma unroll
                for (int e = 0; e < 8; ++e) {
                    *ldsAddr(Vt, d0 + e, key)     = v0[e];
                    *ldsAddr(Vt, d0 + 8 + e, key) = v1[e];
                }
            } else {
                #pragma unroll
                for (int e = 0; e < 16; ++e) *ldsAddr(Vt, d0 + e, key) = 0;
            }
        }
        __syncthreads();

        // ---- QK^T: S[16q x 64k] per wave ----
        short8 af[2];
        #pragma unroll
        for (int ks = 0; ks < 2; ++ks)
            af[ks] = *(const short8*)ldsAddr(Qs, w * 16 + lm, ks * 32 + lg * 8);
        f32x4 sacc[4];
        #pragma unroll
        for (int j = 0; j < 4; ++j) {
            f32x4 z = {};
            #pragma unroll
            for (int ks = 0; ks < 2; ++ks) {
                short8 kf = *(const short8*)ldsAddr(Ks, j * 16 + lm, ks * 32 + lg * 8);
                z = __builtin_amdgcn_mfma_f32_16x16x32_bf16(af[ks], kf, z, 0, 0, 0);
            }
            sacc[j] = z;
        }

        // ---- scale + mask; frag layout: col(key)=lm+j*16, row(q)=lg*4+r ----
        float p[4][4];   // [j][r]
        int pmj[4], kgj[4];
        #pragma unroll
        for (int j = 0; j < 4; ++j) {
            kgj[j] = kstart + j * 16 + lm;
            pmj[j] = (kgj[j] >= 0 && kgj[j] < SEQ) ? pmask[b * SEQ + kgj[j]] : 0;
        }
        float mt[4] = {-3.0e38f, -3.0e38f, -3.0e38f, -3.0e38f};
        #pragma unroll
        for (int j = 0; j < 4; ++j)
            #pragma unroll
            for (int r = 0; r < 4; ++r) {
                const int qg = q0 + w * 16 + lg * 4 + r;
                const int diff = qg - kgj[j];
                float v = sacc[j][r] * 0.125f;
                const bool valid = (pmj[j] != 0) && (diff <= HALFW) && (diff >= -HALFW);
                v = valid ? v : -3.0e38f;
                p[j][r] = v;
                mt[r] = fmaxf(mt[r], v);
            }

        // ---- online softmax (rows live in 16-lane groups) ----
        #pragma unroll
        for (int r = 0; r < 4; ++r) {
            float m = mt[r];
            m = fmaxf(m, __shfl_xor(m, 1));
            m = fmaxf(m, __shfl_xor(m, 2));
            m = fmaxf(m, __shfl_xor(m, 4));
            m = fmaxf(m, __shfl_xor(m, 8));
            const float Mnew = fmaxf(Mrun[r], m);
            float ps = 0.f;
            #pragma unroll
            for (int j = 0; j < 4; ++j) {
                float e = (p[j][r] > -1.0e37f) ? expf(p[j][r] - Mnew) : 0.0f;
                p[j][r] = e; ps += e;
            }
            ps += __shfl_xor(ps, 1); ps += __shfl_xor(ps, 2);
            ps += __shfl_xor(ps, 4); ps += __shfl_xor(ps, 8);
            const float scale = expf(Mrun[r] - Mnew);
            Lrun[r] = Lrun[r] * scale + ps;
            Mrun[r] = Mnew;
            #pragma unroll
            for (int jd = 0; jd < 4; ++jd) oacc[jd][r] *= scale;
        }

        // ---- P -> LDS (bf16, wave-local rows; no barrier needed) ----
        #pragma unroll
        for (int j = 0; j < 4; ++j)
            #pragma unroll
            for (int r = 0; r < 4; ++r)
                *ldsAddr(Ps, w * 16 + lg * 4 + r, j * 16 + lm) = f2bf(p[j][r]);

        // ---- PV: O[16q x 64d] += P @ V ----
        #pragma unroll
        for (int ks = 0; ks < 2; ++ks) {
            short8 pa = *(const short8*)ldsAddr(Ps, w * 16 + lm, ks * 32 + lg * 8);
            #pragma unroll
            for (int jd = 0; jd < 4; ++jd) {
                short8 vb = *(const short8*)ldsAddr(Vt, jd * 16 + lm, ks * 32 + lg * 8);
                oacc[jd] = __builtin_amdgcn_mfma_f32_16x16x32_bf16(pa, vb, oacc[jd], 0, 0, 0);
            }
        }
    }

    // ---- normalize + store bf16 ----
    #pragma unroll
    for (int r = 0; r < 4; ++r) {
        const float inv = (Lrun[r] > 0.f) ? 1.0f / Lrun[r] : 0.0f;
        const size_t row = (size_t)(b * SEQ + q0 + w * 16 + lg * 4 + r);
        #pragma unroll
        for (int jd = 0; jd < 4; ++jd)
            out[row * DM + h * DH + jd * 16 + lm] = f2bf(oacc[jd][r] * inv);
    }
}

// ---------------- driver ----------------
extern "C" void kernel_launch(void* const* d_in, const int* in_sizes, int n_in,
                              void* d_out, int out_size, void* d_ws, size_t ws_size,
                              hipStream_t stream) {
    const float* x      = (const float*)d_in[0];
    const int*   pmask  = (const int*)  d_in[1];
    const float* w_qkv  = (const float*)d_in[2];
    const float* w_o    = (const float*)d_in[3];
    const float* g_attn = (const float*)d_in[4];
    const float* g_mlp  = (const float*)d_in[5];
    const float* w_i0   = (const float*)d_in[6];
    const float* w_i1   = (const float*)d_in[7];
    const float* w_mo   = (const float*)d_in[8];
    float* out = (float*)d_out;

    char* ws = (char*)d_ws;
    u16* Wqkv = (u16*)ws;                ws += (size_t)768 * 2304 * 2;
    u16* Wo   = (u16*)ws;                ws += (size_t)768 * 768 * 2;
    u16* Wi0  = (u16*)ws;                ws += (size_t)768 * 1152 * 2;
    u16* Wi1  = (u16*)ws;                ws += (size_t)768 * 1152 * 2;
    u16* Wmo  = (u16*)ws;                ws += (size_t)1152 * 768 * 2;
    u16* hB    = (u16*)ws;               ws += (size_t)NTOK * DM * 2;
    u16* qkvB  = (u16*)ws;               ws += (size_t)NTOK * 3 * DM * 2;
    u16* attnB = (u16*)ws;               ws += (size_t)NTOK * DM * 2;
    u16* prodB = (u16*)ws;               ws += (size_t)NTOK * DI * 2;
    float* ropeCos = (float*)ws;         ws += (size_t)SEQ * 32 * 4;
    float* ropeSin = (float*)ws;         ws += (size_t)SEQ * 32 * 4;

    // 0. tables + weight transpose/convert
    rope_table_kernel<<<SEQ * 32 / 256, 256, 0, stream>>>(ropeCos, ropeSin);
    wtrans_kernel<<<dim3(2304 / 32, 768 / 32), 256, 0, stream>>>(w_qkv, Wqkv, 768, 2304);
    wtrans_kernel<<<dim3(768 / 32, 768 / 32),  256, 0, stream>>>(w_o,   Wo,   768, 768);
    wtrans_kernel<<<dim3(1152 / 32, 768 / 32), 256, 0, stream>>>(w_i0,  Wi0,  768, 1152);
    wtrans_kernel<<<dim3(1152 / 32, 768 / 32), 256, 0, stream>>>(w_i1,  Wi1,  768, 1152);
    wtrans_kernel<<<dim3(768 / 32, 1152 / 32), 256, 0, stream>>>(w_mo,  Wmo,  1152, 768);

    // 1. h = rmsnorm(x) -> bf16
    rmsnorm_kernel<<<NTOK, 256, 0, stream>>>(x, g_attn, hB);
    // 2. qkv = h @ w_qkv -> bf16
    bgemm_kernel<0, false, true, false><<<dim3(2304 / 128, NTOK / 128), 256, 0, stream>>>(
        hB, Wqkv, nullptr, qkvB, nullptr, NTOK, 2304, 768);
    // 3+4. attention (rope fused) -> bf16
    attn_kernel<<<dim3(SEQ / 64, NHEAD, BATCH), 256, 0, stream>>>(
        qkvB, pmask, ropeCos, ropeSin, attnB);
    // 5. x1 = x + attn @ w_o -> fp32 d_out
    bgemm_kernel<0, true, false, false><<<dim3(768 / 128, NTOK / 128), 256, 0, stream>>>(
        attnB, Wo, nullptr, out, x, NTOK, 768, 768);
    // 6. h2 = rmsnorm(x1) -> bf16
    rmsnorm_kernel<<<NTOK, 256, 0, stream>>>(out, g_mlp, hB);
    // 7+8. prod = gelu(h2 @ w_i0) * (h2 @ w_i1) -> bf16 (dual-B fused)
    bgemm_kernel<3, false, true, true><<<dim3(1152 / 128, NTOK / 128), 256, 0, stream>>>(
        hB, Wi0, Wi1, prodB, nullptr, NTOK, 1152, 768);
    // 9. out = x1 + prod @ w_mo (in-place residual)
    bgemm_kernel<0, true, false, false><<<dim3(768 / 128, NTOK / 128), 256, 0, stream>>>(
        prodB, Wmo, nullptr, out, out, NTOK, 768, 1152);
}

// Round 4
// 332.337 us; speedup vs baseline: 4.3198x; 1.1192x over previous
//
#include <hip/hip_runtime.h>
#include <hip/hip_bf16.h>
#include <math.h>

// ---------------- constants ----------------
#define SEQ   4096
#define BATCH 2
#define DM    768
#define DI    1152
#define NHEAD 12
#define DH    64
#define NTOK  (BATCH * SEQ)   // 8192
#define HALFW 64              // WINDOW//2

typedef unsigned short u16;
typedef __attribute__((ext_vector_type(8))) short   short8;   // 8 bf16 = MFMA A/B frag
typedef __attribute__((ext_vector_type(4))) float   f32x4;    // MFMA C/D frag
typedef __attribute__((ext_vector_type(8))) unsigned short ushort8;

__device__ __forceinline__ u16 f2bf(float f) {
    unsigned int u = __float_as_uint(f);
    u += 0x7fffu + ((u >> 16) & 1u);   // RNE
    return (u16)(u >> 16);
}
__device__ __forceinline__ float bf2f(u16 b) {
    return __uint_as_float(((unsigned int)b) << 16);
}

__device__ __forceinline__ void gload16(const void* g, void* l) {
    __builtin_amdgcn_global_load_lds(
        (const __attribute__((address_space(1))) void*)g,
        (__attribute__((address_space(3))) void*)l, 16, 0, 0);
}

__device__ __forceinline__ float gelu_tanh(float v) {
    return 0.5f * v * (1.0f + tanhf(0.7978845608028654f * (v + 0.044715f * v * v * v)));
}

// ---------------- weight transpose + bf16 convert ----------------
__global__ __launch_bounds__(256)
void wtrans_kernel(const float* __restrict__ W, u16* __restrict__ WT, int K, int N) {
    __shared__ float S[32][33];
    const int tn = blockIdx.x, tk = blockIdx.y;
    const int tx = threadIdx.x & 31, ty = threadIdx.x >> 5;
    #pragma unroll
    for (int i = 0; i < 4; ++i) {
        const int r = ty + i * 8;
        S[r][tx] = W[(size_t)(tk * 32 + r) * N + tn * 32 + tx];
    }
    __syncthreads();
    #pragma unroll
    for (int i = 0; i < 4; ++i) {
        const int r = ty + i * 8;
        WT[(size_t)(tn * 32 + r) * K + tk * 32 + tx] = f2bf(S[tx][r]);
    }
}

// ---------------- rope cos/sin table: [s][j], j=0..31 ----------------
__global__ __launch_bounds__(256)
void rope_table_kernel(float* __restrict__ cosT, float* __restrict__ sinT) {
    const int id = blockIdx.x * 256 + threadIdx.x;   // SEQ*32
    const int j = id & 31, s = id >> 5;
    const float inv = powf(10000.0f, -(float)j * (1.0f / 32.0f));
    const float ph = (float)s * inv;
    cosT[id] = cosf(ph);
    sinT[id] = sinf(ph);
}

// ---------------- RMSNorm (fp32 in -> bf16 out) ----------------
__global__ __launch_bounds__(256)
void rmsnorm_kernel(const float* __restrict__ x, const float* __restrict__ g,
                    u16* __restrict__ out) {
    const int row = blockIdx.x;
    const int t = threadIdx.x;
    const float* xr = x + (size_t)row * DM;
    float a = xr[t], b = xr[t + 256], c = xr[t + 512];
    float ss = a * a + b * b + c * c;
    #pragma unroll
    for (int o = 32; o > 0; o >>= 1) ss += __shfl_xor(ss, o);
    __shared__ float red[4];
    if ((t & 63) == 0) red[t >> 6] = ss;
    __syncthreads();
    float tot = red[0] + red[1] + red[2] + red[3];
    float inv = 1.0f / sqrtf(tot * (1.0f / DM) + 1e-5f);
    u16* orow = out + (size_t)row * DM;
    orow[t]       = f2bf(a * inv * g[t]);
    orow[t + 256] = f2bf(b * inv * g[t + 256]);
    orow[t + 512] = f2bf(c * inv * g[t + 512]);
}

// ---------------- bf16 MFMA GEMM (double-buffered, XCD-swizzled) ----------------
// A bf16 [M][K]; B (and B2) bf16 [N][K] pre-transposed.
// EPI: 0 none, 3 swiglu (gelu(acc1)*acc2, needs DUAL).  RES: += R(fp32).
// OBF: bf16 out else fp32.  1D grid, nbn = N/128 passed in.
template<int EPI, bool RES, bool OBF, bool DUAL>
__global__ __launch_bounds__(256)
void bgemm_kernel(const u16* __restrict__ A, const u16* __restrict__ B,
                  const u16* __restrict__ B2, void* __restrict__ Cv,
                  const float* __restrict__ R, int M, int N, int K, int nbn) {
    __shared__ u16 As[2 * 4096];
    __shared__ u16 Bs[2 * 4096];
    __shared__ u16 B2s[DUAL ? 2 * 4096 : 2];
    const int t = threadIdx.x;
    const int w = t >> 6, l = t & 63;
    const int wm = w >> 1, wn = w & 1;

    // bijective XCD swizzle (m204): each XCD gets a contiguous wgid chunk;
    // bn fastest within chunk -> consecutive same-XCD blocks share the A-tile.
    const int nb = gridDim.x;
    const int orig = blockIdx.x;
    const int qq = nb >> 3, rr = nb & 7;
    const int xcd = orig & 7, cidx = orig >> 3;
    const int wgid = (xcd < rr ? xcd * (qq + 1) : rr * (qq + 1) + (xcd - rr) * qq) + cidx;
    const int bm = wgid / nbn, bn = wgid % nbn;

    // staging: slot s holds row m=s>>2, k-chunk ((s&3) ^ ((s>>3)&3))
    const int s0 = (w * 2 + 0) * 64 + l;
    const int s1 = (w * 2 + 1) * 64 + l;
    const int am0 = s0 >> 2, ak0 = ((s0 & 3) ^ ((s0 >> 3) & 3)) * 8;
    const int am1 = s1 >> 2, ak1 = ((s1 & 3) ^ ((s1 >> 3) & 3)) * 8;
    const u16* aSrc0 = A + (size_t)(bm * 128 + am0) * K + ak0;
    const u16* aSrc1 = A + (size_t)(bm * 128 + am1) * K + ak1;
    const u16* bSrc0 = B + (size_t)(bn * 128 + am0) * K + ak0;
    const u16* bSrc1 = B + (size_t)(bn * 128 + am1) * K + ak1;
    const u16* cSrc0 = DUAL ? B2 + (size_t)(bn * 128 + am0) * K + ak0 : nullptr;
    const u16* cSrc1 = DUAL ? B2 + (size_t)(bn * 128 + am1) * K + ak1 : nullptr;
    const int dS0 = (w * 2 + 0) * 512;   // u16 offset of this thread's wave-row base
    const int dS1 = (w * 2 + 1) * 512;

    const int lm = l & 15, lk = l >> 4;
    const int xoff = ((lk ^ ((lm >> 1) & 3)) * 16);   // byte offset within 64B row

    f32x4 acc[4][4] = {};
    f32x4 acc2[4][4] = {};

    const int nk = K >> 5;

#define STAGE(pp)  do {                                                        \
        u16* a_ = As + (pp) * 4096;  u16* b_ = Bs + (pp) * 4096;               \
        gload16(aSrc0, a_ + dS0);  gload16(aSrc1, a_ + dS1);                   \
        gload16(bSrc0, b_ + dS0);  gload16(bSrc1, b_ + dS1);                   \
        if (DUAL) { u16* c_ = B2s + (pp) * 4096;                               \
                    gload16(cSrc0, c_ + dS0);  gload16(cSrc1, c_ + dS1); }     \
        aSrc0 += 32; aSrc1 += 32; bSrc0 += 32; bSrc1 += 32;                    \
        if (DUAL) { cSrc0 += 32; cSrc1 += 32; }                                \
    } while (0)

    STAGE(0);
    __syncthreads();   // drains vmcnt: buf0 ready
    int p = 0;
    for (int kt = 0; kt < nk; ++kt) {
        if (kt + 1 < nk) STAGE(p ^ 1);   // issue next tile; lands by end-of-iter barrier

        const char* Abase = (const char*)As + p * 8192;
        const char* Bbase = (const char*)Bs + p * 8192;
        const char* Cbase = (const char*)B2s + p * 8192;
        short8 af[4], bfr[4], cfr[4];
        #pragma unroll
        for (int i = 0; i < 4; ++i) {
            af[i]  = *(const short8*)(Abase + (wm * 64 + i * 16 + lm) * 64 + xoff);
            bfr[i] = *(const short8*)(Bbase + (wn * 64 + i * 16 + lm) * 64 + xoff);
            if (DUAL) cfr[i] = *(const short8*)(Cbase + (wn * 64 + i * 16 + lm) * 64 + xoff);
        }
        #pragma unroll
        for (int i = 0; i < 4; ++i)
            #pragma unroll
            for (int j = 0; j < 4; ++j) {
                acc[i][j] = __builtin_amdgcn_mfma_f32_16x16x32_bf16(af[i], bfr[j], acc[i][j], 0, 0, 0);
                if (DUAL)
                    acc2[i][j] = __builtin_amdgcn_mfma_f32_16x16x32_bf16(af[i], cfr[j], acc2[i][j], 0, 0, 0);
            }
        __syncthreads();   // vmcnt(0)+lgkmcnt(0)+barrier: next buf ready, this buf's reads done
        p ^= 1;
    }
#undef STAGE

    const int lg = l >> 4;
    float* Cf = (float*)Cv;
    u16*   Cb = (u16*)Cv;
    #pragma unroll
    for (int i = 0; i < 4; ++i) {
        const size_t row0 = (size_t)bm * 128 + wm * 64 + i * 16 + lg * 4;
        #pragma unroll
        for (int j = 0; j < 4; ++j) {
            const size_t col = (size_t)bn * 128 + wn * 64 + j * 16 + lm;
            #pragma unroll
            for (int r = 0; r < 4; ++r) {
                const size_t idx = (row0 + r) * (size_t)N + col;
                float v = acc[i][j][r];
                if (EPI == 3) v = gelu_tanh(v) * acc2[i][j][r];
                if (RES)      v += R[idx];
                if (OBF) Cb[idx] = f2bf(v);
                else     Cf[idx] = v;
            }
        }
    }
}

// ---------------- MFMA sliding-window attention w/ fused RoPE ----------------
__device__ __forceinline__ u16* ldsAddr(u16* base, int row, int col) {
    const int ch = (col >> 3) ^ (row & 7);
    return base + row * 64 + ch * 8 + (col & 7);
}

__global__ __launch_bounds__(256)
void attn_kernel(const u16* __restrict__ qkv, const int* __restrict__ pmask,
                 const float* __restrict__ cosT, const float* __restrict__ sinT,
                 u16* __restrict__ out) {
    const int qt = blockIdx.x, h = blockIdx.y, b = blockIdx.z;
    const int q0 = qt * 64;
    const int t = threadIdx.x;
    const int w = t >> 6, l = t & 63;
    const int lm = l & 15, lg = l >> 4;

    __shared__ u16 Qs[64 * 64];
    __shared__ u16 Ks[64 * 64];
    __shared__ u16 Vt[64 * 64];   // transposed: rows = d, cols = key
    __shared__ u16 Ps[64 * 64];

    // ---- stage Q with rope ----
    {
        const int r = t >> 2, j0 = (t & 3) * 8;
        const int s = q0 + r;
        const u16* qrow = qkv + (size_t)(b * SEQ + s) * (3 * DM) + h * DH;
        ushort8 lo = *(const ushort8*)(qrow + j0);
        ushort8 hi = *(const ushort8*)(qrow + j0 + 32);
        const float* cr = cosT + (size_t)s * 32 + j0;
        const float* sr = sinT + (size_t)s * 32 + j0;
        ushort8 olo, ohi;
        #pragma unroll
        for (int e = 0; e < 8; ++e) {
            float c = cr[e], sn = sr[e];
            float xl = bf2f(lo[e]), xh = bf2f(hi[e]);
            olo[e] = f2bf(xl * c - xh * sn);
            ohi[e] = f2bf(xh * c + xl * sn);
        }
        *(ushort8*)ldsAddr(Qs, r, j0)      = olo;
        *(ushort8*)ldsAddr(Qs, r, j0 + 32) = ohi;
    }

    f32x4 oacc[4] = {};
    float Mrun[4], Lrun[4];
    #pragma unroll
    for (int r = 0; r < 4; ++r) { Mrun[r] = -3.0e38f; Lrun[r] = 0.f; }

    for (int kb = 0; kb < 3; ++kb) {
        const int kstart = q0 - 64 + kb * 64;
        __syncthreads();
        // ---- stage K with rope ----
        {
            const int r = t >> 2, j0 = (t & 3) * 8;
            const int kg = kstart + r;
            ushort8 olo = {}, ohi = {};
            if (kg >= 0 && kg < SEQ) {
                const u16* krow = qkv + (size_t)(b * SEQ + kg) * (3 * DM) + DM + h * DH;
                ushort8 lo = *(const ushort8*)(krow + j0);
                ushort8 hi = *(const ushort8*)(krow + j0 + 32);
                const float* cr = cosT + (size_t)kg * 32 + j0;
                const float* sr = sinT + (size_t)kg * 32 + j0;
                #pragma unroll
                for (int e = 0; e < 8; ++e) {
                    float c = cr[e], sn = sr[e];
                    float xl = bf2f(lo[e]), xh = bf2f(hi[e]);
                    olo[e] = f2bf(xl * c - xh * sn);
                    ohi[e] = f2bf(xh * c + xl * sn);
                }
            }
            *(ushort8*)ldsAddr(Ks, r, j0)      = olo;
            *(ushort8*)ldsAddr(Ks, r, j0 + 32) = ohi;
        }
        // ---- stage V transposed ----
        {
            const int key = l;
            const int kg = kstart + key;
            const int d0 = w * 16;
            if (kg >= 0 && kg < SEQ) {
                const u16* vrow = qkv + (size_t)(b * SEQ + kg) * (3 * DM) + 2 * DM + h * DH + d0;
                ushort8 v0 = *(const ushort8*)(vrow);
                ushort8 v1 = *(const ushort8*)(vrow + 8);
                #pragma unroll
                for (int e = 0; e < 8; ++e) {
                    *ldsAddr(Vt, d0 + e, key)     = v0[e];
                    *ldsAddr(Vt, d0 + 8 + e, key) = v1[e];
                }
            } else {
                #pragma unroll
                for (int e = 0; e < 16; ++e) *ldsAddr(Vt, d0 + e, key) = 0;
            }
        }
        __syncthreads();

        // ---- QK^T ----
        short8 af[2];
        #pragma unroll
        for (int ks = 0; ks < 2; ++ks)
            af[ks] = *(const short8*)ldsAddr(Qs, w * 16 + lm, ks * 32 + lg * 8);
        f32x4 sacc[4];
        #pragma unroll
        for (int j = 0; j < 4; ++j) {
            f32x4 z = {};
            #pragma unroll
            for (int ks = 0; ks < 2; ++ks) {
                short8 kf = *(const short8*)ldsAddr(Ks, j * 16 + lm, ks * 32 + lg * 8);
                z = __builtin_amdgcn_mfma_f32_16x16x32_bf16(af[ks], kf, z, 0, 0, 0);
            }
            sacc[j] = z;
        }

        // ---- scale + mask ----
        float p[4][4];
        int pmj[4], kgj[4];
        #pragma unroll
        for (int j = 0; j < 4; ++j) {
            kgj[j] = kstart + j * 16 + lm;
            pmj[j] = (kgj[j] >= 0 && kgj[j] < SEQ) ? pmask[b * SEQ + kgj[j]] : 0;
        }
        float mt[4] = {-3.0e38f, -3.0e38f, -3.0e38f, -3.0e38f};
        #pragma unroll
        for (int j = 0; j < 4; ++j)
            #pragma unroll
            for (int r = 0; r < 4; ++r) {
                const int qg = q0 + w * 16 + lg * 4 + r;
                const int diff = qg - kgj[j];
                float v = sacc[j][r] * 0.125f;
                const bool valid = (pmj[j] != 0) && (diff <= HALFW) && (diff >= -HALFW);
                v = valid ? v : -3.0e38f;
                p[j][r] = v;
                mt[r] = fmaxf(mt[r], v);
            }

        // ---- online softmax ----
        #pragma unroll
        for (int r = 0; r < 4; ++r) {
            float m = mt[r];
            m = fmaxf(m, __shfl_xor(m, 1));
            m = fmaxf(m, __shfl_xor(m, 2));
            m = fmaxf(m, __shfl_xor(m, 4));
            m = fmaxf(m, __shfl_xor(m, 8));
            const float Mnew = fmaxf(Mrun[r], m);
            float ps = 0.f;
            #pragma unroll
            for (int j = 0; j < 4; ++j) {
                float e = (p[j][r] > -1.0e37f) ? expf(p[j][r] - Mnew) : 0.0f;
                p[j][r] = e; ps += e;
            }
            ps += __shfl_xor(ps, 1); ps += __shfl_xor(ps, 2);
            ps += __shfl_xor(ps, 4); ps += __shfl_xor(ps, 8);
            const float scale = expf(Mrun[r] - Mnew);
            Lrun[r] = Lrun[r] * scale + ps;
            Mrun[r] = Mnew;
            #pragma unroll
            for (int jd = 0; jd < 4; ++jd) oacc[jd][r] *= scale;
        }

        // ---- P -> LDS (wave-local rows) ----
        #pragma unroll
        for (int j = 0; j < 4; ++j)
            #pragma unroll
            for (int r = 0; r < 4; ++r)
                *ldsAddr(Ps, w * 16 + lg * 4 + r, j * 16 + lm) = f2bf(p[j][r]);

        // ---- PV ----
        #pragma unroll
        for (int ks = 0; ks < 2; ++ks) {
            short8 pa = *(const short8*)ldsAddr(Ps, w * 16 + lm, ks * 32 + lg * 8);
            #pragma unroll
            for (int jd = 0; jd < 4; ++jd) {
                short8 vb = *(const short8*)ldsAddr(Vt, jd * 16 + lm, ks * 32 + lg * 8);
                oacc[jd] = __builtin_amdgcn_mfma_f32_16x16x32_bf16(pa, vb, oacc[jd], 0, 0, 0);
            }
        }
    }

    // ---- normalize + store bf16 ----
    #pragma unroll
    for (int r = 0; r < 4; ++r) {
        const float inv = (Lrun[r] > 0.f) ? 1.0f / Lrun[r] : 0.0f;
        const size_t row = (size_t)(b * SEQ + q0 + w * 16 + lg * 4 + r);
        #pragma unroll
        for (int jd = 0; jd < 4; ++jd)
            out[row * DM + h * DH + jd * 16 + lm] = f2bf(oacc[jd][r] * inv);
    }
}

// ---------------- driver ----------------
extern "C" void kernel_launch(void* const* d_in, const int* in_sizes, int n_in,
                              void* d_out, int out_size, void* d_ws, size_t ws_size,
                              hipStream_t stream) {
    const float* x      = (const float*)d_in[0];
    const int*   pmask  = (const int*)  d_in[1];
    const float* w_qkv  = (const float*)d_in[2];
    const float* w_o    = (const float*)d_in[3];
    const float* g_attn = (const float*)d_in[4];
    const float* g_mlp  = (const float*)d_in[5];
    const float* w_i0   = (const float*)d_in[6];
    const float* w_i1   = (const float*)d_in[7];
    const float* w_mo   = (const float*)d_in[8];
    float* out = (float*)d_out;

    char* ws = (char*)d_ws;
    u16* Wqkv = (u16*)ws;                ws += (size_t)768 * 2304 * 2;
    u16* Wo   = (u16*)ws;                ws += (size_t)768 * 768 * 2;
    u16* Wi0  = (u16*)ws;                ws += (size_t)768 * 1152 * 2;
    u16* Wi1  = (u16*)ws;                ws += (size_t)768 * 1152 * 2;
    u16* Wmo  = (u16*)ws;                ws += (size_t)1152 * 768 * 2;
    u16* hB    = (u16*)ws;               ws += (size_t)NTOK * DM * 2;
    u16* qkvB  = (u16*)ws;               ws += (size_t)NTOK * 3 * DM * 2;
    u16* attnB = (u16*)ws;               ws += (size_t)NTOK * DM * 2;
    u16* prodB = (u16*)ws;               ws += (size_t)NTOK * DI * 2;
    float* ropeCos = (float*)ws;         ws += (size_t)SEQ * 32 * 4;
    float* ropeSin = (float*)ws;         ws += (size_t)SEQ * 32 * 4;

    // 0. tables + weight transpose/convert
    rope_table_kernel<<<SEQ * 32 / 256, 256, 0, stream>>>(ropeCos, ropeSin);
    wtrans_kernel<<<dim3(2304 / 32, 768 / 32), 256, 0, stream>>>(w_qkv, Wqkv, 768, 2304);
    wtrans_kernel<<<dim3(768 / 32, 768 / 32),  256, 0, stream>>>(w_o,   Wo,   768, 768);
    wtrans_kernel<<<dim3(1152 / 32, 768 / 32), 256, 0, stream>>>(w_i0,  Wi0,  768, 1152);
    wtrans_kernel<<<dim3(1152 / 32, 768 / 32), 256, 0, stream>>>(w_i1,  Wi1,  768, 1152);
    wtrans_kernel<<<dim3(768 / 32, 1152 / 32), 256, 0, stream>>>(w_mo,  Wmo,  1152, 768);

    // 1. h = rmsnorm(x) -> bf16
    rmsnorm_kernel<<<NTOK, 256, 0, stream>>>(x, g_attn, hB);
    // 2. qkv = h @ w_qkv -> bf16   (1D grid, nbn = 18)
    bgemm_kernel<0, false, true, false><<<(NTOK / 128) * (2304 / 128), 256, 0, stream>>>(
        hB, Wqkv, nullptr, qkvB, nullptr, NTOK, 2304, 768, 2304 / 128);
    // 3+4. attention (rope fused) -> bf16
    attn_kernel<<<dim3(SEQ / 64, NHEAD, BATCH), 256, 0, stream>>>(
        qkvB, pmask, ropeCos, ropeSin, attnB);
    // 5. x1 = x + attn @ w_o -> fp32 d_out   (nbn = 6)
    bgemm_kernel<0, true, false, false><<<(NTOK / 128) * (768 / 128), 256, 0, stream>>>(
        attnB, Wo, nullptr, out, x, NTOK, 768, 768, 768 / 128);
    // 6. h2 = rmsnorm(x1) -> bf16
    rmsnorm_kernel<<<NTOK, 256, 0, stream>>>(out, g_mlp, hB);
    // 7+8. prod = gelu(h2 @ w_i0) * (h2 @ w_i1) -> bf16   (nbn = 9)
    bgemm_kernel<3, false, true, true><<<(NTOK / 128) * (1152 / 128), 256, 0, stream>>>(
        hB, Wi0, Wi1, prodB, nullptr, NTOK, 1152, 768, 1152 / 128);
    // 9. out = x1 + prod @ w_mo (in-place residual)   (nbn = 6)
    bgemm_kernel<0, true, false, false><<<(NTOK / 128) * (768 / 128), 256, 0, stream>>>(
        prodB, Wmo, nullptr, out, out, NTOK, 768, 1152, 768 / 128);
}